// Round 16
// baseline (462.732 us; speedup 1.0000x reference)
//
#include <hip/hip_runtime.h>

typedef unsigned short u16;
typedef unsigned int   u32;
typedef __attribute__((ext_vector_type(8))) short s16x8;   // 8 x bf16 MFMA frag
typedef __attribute__((ext_vector_type(4))) float f32x4;

__device__ __forceinline__ u16 f2bf(float f) {
  u32 u = __builtin_bit_cast(u32, f);
  return (u16)((u + 0x7FFFu + ((u >> 16) & 1u)) >> 16);   // RNE
}
__device__ __forceinline__ float bf2f(u16 h) {
  return __builtin_bit_cast(float, (u32)h << 16);
}
__device__ __forceinline__ u32 pack2(float a, float b) {
  return (u32)f2bf(a) | ((u32)f2bf(b) << 16);
}

// ---------------- K0: weight f32 -> bf16 ----------------
__global__ __launch_bounds__(256) void k_wcvt(const float* __restrict__ wq,
                                              const float* __restrict__ wp,
                                              u16* __restrict__ wq_bf,
                                              u16* __restrict__ wp_bf) {
  int i = blockIdx.x * 256 + threadIdx.x;
  if (i < 576 * 192) wq_bf[i] = f2bf(wq[i]);
  if (i < 192 * 192) wp_bf[i] = f2bf(wp[i]);
}

// ---------------- K1: qkv 1x1 conv (GEMM M=576,K=192), W-in-registers ------
// (R14/R15-verified: swizzled LDS, 12 waves, wf once, zero barriers after gather.)
__global__ __launch_bounds__(768, 3) void k_qkv(const float* __restrict__ x,
                                                const u16* __restrict__ wq,
                                                u16* __restrict__ qkv1) {
  __shared__ __align__(16) u16 Xs[256 * 200];        // [n=256][k=192 pad 200]
  const int t  = threadIdx.x;
  const int b  = blockIdx.y;
  const int h1 = blockIdx.x;
  const float* xb = x + (size_t)b * 12582912;
  const int hbase = h1 >> 2;
  const int wbase = (h1 & 3) << 4;
#pragma unroll
  for (int it = 0; it < 8; ++it) {
    const int idx = it * 768 + t;          // 6144 units: f(4) x r(16) x c2(96)
    const int f = idx & 3;
    const int r = (idx >> 2) & 15;
    const int c = (idx >> 6) * 2;
    const int ho = ((r >> 2) & 3) * 64 + hbase;
    const int wo = (r & 3) * 64 + wbase + f * 4;
    const float* s0 = xb + (size_t)c * 65536 + (size_t)ho * 256 + wo;
    float4 v0 = *(const float4*)s0;
    float4 v1 = *(const float4*)(s0 + 65536);
    const int nb = 64 * f + r;
    const int slot = c >> 3;
    const int sl = (slot & 24) | ((slot + 2 * (r & 7)) & 7);
    const int ccol = sl * 8 + (c & 7);
    *(u32*)&Xs[(nb     ) * 200 + ccol] = pack2(v0.x, v1.x);
    *(u32*)&Xs[(nb + 16) * 200 + ccol] = pack2(v0.y, v1.y);
    *(u32*)&Xs[(nb + 32) * 200 + ccol] = pack2(v0.z, v1.z);
    *(u32*)&Xs[(nb + 48) * 200 + ccol] = pack2(v0.w, v1.w);
  }
  __syncthreads();
  const int lane = t & 63, wv = t >> 6;    // 12 waves, ch slice each
  const int lm = lane & 15, lk = lane >> 4;
  s16x8 wf[3][6];
#pragma unroll
  for (int mf = 0; mf < 3; ++mf) {
#pragma unroll
    for (int kk = 0; kk < 6; ++kk)
      wf[mf][kk] = *(const s16x8*)&wq[(size_t)(wv * 48 + mf * 16 + lm) * 192 + kk * 32 + lk * 8];
  }
  u16* const ob = qkv1 + (size_t)b * 37748736 + h1 * 256 + lk * 4;
  int slr[6];
#pragma unroll
  for (int kk = 0; kk < 6; ++kk) {
    const int slot = 4 * kk + lk;
    slr[kk] = ((slot & 24) | ((slot + 2 * (lm & 7)) & 7)) * 8;
  }

#pragma unroll 2
  for (int g = 0; g < 16; ++g) {
    s16x8 av[6];
#pragma unroll
    for (int kk = 0; kk < 6; ++kk)
      av[kk] = *(const s16x8*)&Xs[(g * 16 + lm) * 200 + slr[kk]];
    f32x4 acc[3];
#pragma unroll
    for (int mf = 0; mf < 3; ++mf) acc[mf] = f32x4{0.f, 0.f, 0.f, 0.f};
#pragma unroll
    for (int kk = 0; kk < 6; ++kk) {
#pragma unroll
      for (int mf = 0; mf < 3; ++mf)
        acc[mf] = __builtin_amdgcn_mfma_f32_16x16x32_bf16(av[kk], wf[mf][kk], acc[mf], 0, 0, 0);
    }
#pragma unroll
    for (int mf = 0; mf < 3; ++mf) {
      const int ch = wv * 48 + mf * 16 + lm;
      uint2 o;
      o.x = pack2(acc[mf][0], acc[mf][1]);
      o.y = pack2(acc[mf][2], acc[mf][3]);
      *(uint2*)(ob + (size_t)ch * 65536 + g * 16) = o;
    }
  }
}

// ---------------- K2: fused depthwise 3x3 + raw-reshape MSA ---------------
// R15 structure + depth-1 software pipeline in the dw phase: octet k+1's
// loads (3 uint4 + 6 edge u16 + masks) issue BEFORE octet k's compute, so
// each ~130-op compute burst hides the next loads' L2 latency.
struct Oct {
  uint4 m0, m1, m2;
  u16 lr0, rr0, lr1, rr1, lr2, rr2;
  int ii, ch;
  float vm, vp, lmask, rmask;
};

__device__ __forceinline__ Oct load_oct(const u16* __restrict__ qb, u32 F, int tl, int k) {
  Oct o;
  o.ii = (tl + 256 * k) * 8;
  const u32 f = F + (u32)o.ii;
  o.ch = (int)(f >> 16);
  const int px = (int)(f & 65535u);
  const int h = px >> 8, w0 = px & 255;
  const u16* in = qb + ((size_t)o.ch << 16);
  const int hm = (h > 0) ? h - 1 : 0;
  const int hp = (h < 255) ? h + 1 : 255;
  const u16* rowm = in + (size_t)hm * 256 + w0;
  const u16* rowc = in + (size_t)h  * 256 + w0;
  const u16* rowp = in + (size_t)hp * 256 + w0;
  const int loff = (w0 > 0) ? -1 : 0;
  const int roff = (w0 < 248) ? 8 : 7;
  o.m0 = *(const uint4*)rowm;
  o.m1 = *(const uint4*)rowc;
  o.m2 = *(const uint4*)rowp;
  o.lr0 = rowm[loff]; o.rr0 = rowm[roff];
  o.lr1 = rowc[loff]; o.rr1 = rowc[roff];
  o.lr2 = rowp[loff]; o.rr2 = rowp[roff];
  o.vm = (h > 0)   ? 1.f : 0.f;
  o.vp = (h < 255) ? 1.f : 0.f;
  o.lmask = (w0 > 0) ? 1.f : 0.f;
  o.rmask = (w0 < 248) ? 1.f : 0.f;
  return o;
}

__device__ __forceinline__ void compute_oct(const Oct& o, const float* __restrict__ wa,
                                            const float* __restrict__ wb, int ch0,
                                            u16* __restrict__ dsrow) {
  const bool sec = (o.ch != ch0);
  float w9[9];
#pragma unroll
  for (int i = 0; i < 9; ++i) w9[i] = sec ? wb[i] : wa[i];
  w9[0] *= o.vm; w9[1] *= o.vm; w9[2] *= o.vm;
  w9[6] *= o.vp; w9[7] *= o.vp; w9[8] *= o.vp;
  float acc[8] = {0.f,0.f,0.f,0.f,0.f,0.f,0.f,0.f};
  const uint4 mids[3] = {o.m0, o.m1, o.m2};
  const u16 lrs[3] = {o.lr0, o.lr1, o.lr2};
  const u16 rrs[3] = {o.rr0, o.rr1, o.rr2};
#pragma unroll
  for (int ky = 0; ky < 3; ++ky) {
    float e[10];
    e[0] = bf2f(lrs[ky]) * o.lmask;
    u32 uu[4] = {mids[ky].x, mids[ky].y, mids[ky].z, mids[ky].w};
#pragma unroll
    for (int q = 0; q < 4; ++q) {
      e[1 + 2 * q] = bf2f((u16)(uu[q] & 0xffffu));
      e[2 + 2 * q] = bf2f((u16)(uu[q] >> 16));
    }
    e[9] = bf2f(rrs[ky]) * o.rmask;
#pragma unroll
    for (int kx = 0; kx < 3; ++kx) {
      const float wk = w9[ky * 3 + kx];
#pragma unroll
      for (int jj = 0; jj < 8; ++jj) acc[jj] += wk * e[jj + kx];
    }
  }
  u32 oo[4];
#pragma unroll
  for (int q = 0; q < 4; ++q)
    oo[q] = pack2(acc[2 * q], acc[2 * q + 1]);
  *(uint4*)&dsrow[o.ii] = make_uint4(oo[0], oo[1], oo[2], oo[3]);
}

__global__ __launch_bounds__(512, 4) void k_dwmsa(const u16* __restrict__ qkv1,
                                                  const float* __restrict__ wdw,
                                                  u16* __restrict__ attnb) {
  __shared__ __align__(16) u16 Ds[2][18432];   // 73728 B
  const int t = threadIdx.x;
  const int b = blockIdx.y;
  const int gh = blockIdx.x >> 3;              // window-row 0..127
  const int c0 = (blockIdx.x & 7) * 32;        // col chunk
  const u16* qb = qkv1 + (size_t)b * 37748736;

  // ---- dw phase: pipelined 9-octet loop ----
  {
    const int s1 = t >> 8;                     // strip (0..1)
    const int tl = t & 255;
    const u32 F = 576u * (u32)((2 * gh + s1) * 256 + c0);
    const int ch0 = (int)(F >> 16);
    const int ch1 = (ch0 < 575) ? ch0 + 1 : 575;
    float wa[9], wb[9];
#pragma unroll
    for (int i = 0; i < 9; ++i) { wa[i] = wdw[ch0 * 9 + i]; wb[i] = wdw[ch1 * 9 + i]; }
    u16* const dsrow = &Ds[s1][0];
    Oct cur = load_oct(qb, F, tl, 0);
#pragma unroll
    for (int k = 0; k < 9; ++k) {
      Oct nxt;
      if (k < 8) nxt = load_oct(qb, F, tl, k + 1);
      compute_oct(cur, wa, wb, ch0, dsrow);
      if (k < 8) cur = nxt;
    }
  }
  __syncthreads();

  // ---- msa phase (R12/R13-verified) ----
  const int lc   = t & 3;
  const int head = (t >> 2) & 7;
  const int win  = t >> 5;                     // 0..15
  const int chq  = head * 24 + lc * 6;         // even
  float qv[4][6], kv[4][6], vv[4][6];
#pragma unroll
  for (int s1 = 0; s1 < 2; ++s1) {
#pragma unroll
    for (int s2 = 0; s2 < 2; ++s2) {
      const int tt = s1 * 2 + s2;
      const int base = (2 * win + s2) * 576 + chq;
#pragma unroll
      for (int pp = 0; pp < 3; ++pp) {
        u32 aq = *(const u32*)&Ds[s1][base + 2 * pp];
        u32 ak = *(const u32*)&Ds[s1][base + 192 + 2 * pp];
        u32 av = *(const u32*)&Ds[s1][base + 384 + 2 * pp];
        qv[tt][2 * pp]     = bf2f((u16)(aq & 0xffffu));
        qv[tt][2 * pp + 1] = bf2f((u16)(aq >> 16));
        kv[tt][2 * pp]     = bf2f((u16)(ak & 0xffffu));
        kv[tt][2 * pp + 1] = bf2f((u16)(ak >> 16));
        vv[tt][2 * pp]     = bf2f((u16)(av & 0xffffu));
        vv[tt][2 * pp + 1] = bf2f((u16)(av >> 16));
      }
    }
  }
  float s[4][4];
#pragma unroll
  for (int tq = 0; tq < 4; ++tq) {
#pragma unroll
    for (int tk = 0; tk < 4; ++tk) {
      float d = 0.f;
#pragma unroll
      for (int dd = 0; dd < 6; ++dd) d += qv[tq][dd] * kv[tk][dd];
      d += __shfl_xor(d, 1);
      d += __shfl_xor(d, 2);
      s[tq][tk] = d * 0.35355339059327373f;    // SCALE = HEADS^-0.5
    }
  }
  u16* const ab = attnb + (size_t)b * 12582912;
#pragma unroll
  for (int tq = 0; tq < 4; ++tq) {
    float mx = fmaxf(fmaxf(s[tq][0], s[tq][1]), fmaxf(s[tq][2], s[tq][3]));
    float e0 = __expf(s[tq][0] - mx), e1 = __expf(s[tq][1] - mx);
    float e2 = __expf(s[tq][2] - mx), e3 = __expf(s[tq][3] - mx);
    float inv = 1.f / (e0 + e1 + e2 + e3);
    float a0 = e0 * inv, a1 = e1 * inv, a2 = e2 * inv, a3 = e3 * inv;
    float o6[6];
#pragma unroll
    for (int dd = 0; dd < 6; ++dd)
      o6[dd] = a0 * vv[0][dd] + a1 * vv[1][dd] + a2 * vv[2][dd] + a3 * vv[3][dd];
    const int s1 = tq >> 1, s2 = tq & 1;
    const size_t pg = (size_t)((2 * gh + s1) * 256) + c0 + 2 * win + s2;
    u16* dst = ab + pg * 192 + chq;
    *(u32*)(dst)     = pack2(o6[0], o6[1]);
    *(u32*)(dst + 2) = pack2(o6[2], o6[3]);
    *(u32*)(dst + 4) = pack2(o6[4], o6[5]);
  }
}

// ---------------- K4: proj 1x1 (GEMM M=192,K=192) + shuffle_back ----------
// (R14-verified: barrier-free direct scatter, swizzled LDS.)
__global__ __launch_bounds__(512) void k_proj(const u16* __restrict__ attnb,
                                              const u16* __restrict__ wp,
                                              float* __restrict__ out) {
  __shared__ __align__(16) u16 Xs[256 * 200];
  const int t  = threadIdx.x;
  const int b  = blockIdx.y;
  const int hs = blockIdx.x;
  const int pix = t & 255, cg = t >> 8;
  {
    const u16* ab = attnb + (size_t)b * 12582912 + (size_t)hs * 256 + pix;
    u16* xrow = &Xs[pix * 200];
    const int key = (pix >> 4) & 7;
#pragma unroll 8
    for (int i = 0; i < 96; i += 2) {
      const int c = cg * 96 + i;
      const int slot = c >> 3;
      const int sl = (slot & 24) | ((slot + key) & 7);
      u16 v0 = ab[(size_t)c * 65536];
      u16 v1 = ab[(size_t)(c + 1) * 65536];
      *(u32*)&xrow[sl * 8 + (c & 7)] = (u32)v0 | ((u32)v1 << 16);
    }
  }
  __syncthreads();
  const int lane = t & 63, wid = t >> 6;
  const int lm = lane & 15, lk = lane >> 4;
  s16x8 bv[2][6];
#pragma unroll
  for (int rp = 0; rp < 2; ++rp) {
    const int r = 2 * wid + rp;
#pragma unroll
    for (int kk = 0; kk < 6; ++kk) {
      const int slot = 4 * kk + lk;
      const int sl = (slot & 24) | ((slot + (lm & 7)) & 7);
      bv[rp][kk] = *(const s16x8*)&Xs[(16 * lm + r) * 200 + sl * 8];
    }
  }
  float* const ob = out + (size_t)b * 12582912;
  const int hq_base = hs >> 2;
  const int wq_base = (hs & 3) << 4;
  int hqr[2], wq0[2];
#pragma unroll
  for (int rp = 0; rp < 2; ++rp) {
    const int r = 2 * wid + rp;
    hqr[rp] = ((r >> 2) & 3) * 64 + hq_base;
    wq0[rp] = (r & 3) * 64 + wq_base;
  }

#pragma unroll 1
  for (int mt = 0; mt < 3; ++mt) {
    f32x4 acc[4][2];
#pragma unroll
    for (int i = 0; i < 4; ++i) {
      acc[i][0] = f32x4{0.f, 0.f, 0.f, 0.f};
      acc[i][1] = f32x4{0.f, 0.f, 0.f, 0.f};
    }
#pragma unroll
    for (int kk = 0; kk < 6; ++kk) {
      s16x8 af[4];
#pragma unroll
      for (int mf = 0; mf < 4; ++mf)
        af[mf] = *(const s16x8*)&wp[(size_t)(mt * 64 + mf * 16 + lm) * 192 + kk * 32 + lk * 8];
#pragma unroll
      for (int mf = 0; mf < 4; ++mf) {
#pragma unroll
        for (int rp = 0; rp < 2; ++rp)
          acc[mf][rp] = __builtin_amdgcn_mfma_f32_16x16x32_bf16(af[mf], bv[rp][kk], acc[mf][rp], 0, 0, 0);
      }
    }
#pragma unroll
    for (int mf = 0; mf < 4; ++mf) {
#pragma unroll
      for (int rp = 0; rp < 2; ++rp) {
        float* base = ob + (size_t)(mt * 64 + mf * 16 + lk * 4) * 65536
                         + (size_t)hqr[rp] * 256 + wq0[rp] + lm;
#pragma unroll
        for (int rr = 0; rr < 4; ++rr)
          base[(size_t)rr * 65536] = acc[mf][rp][rr];
      }
    }
  }
}

extern "C" void kernel_launch(void* const* d_in, const int* in_sizes, int n_in,
                              void* d_out, int out_size, void* d_ws, size_t ws_size,
                              hipStream_t stream) {
  const float* x   = (const float*)d_in[0];
  const float* wq  = (const float*)d_in[1];
  const float* wdw = (const float*)d_in[2];
  const float* wpr = (const float*)d_in[3];
  float* out = (float*)d_out;
  u16* ws = (u16*)d_ws;
  // layout (u16): wq_bf | wp_bf | qkv1 (302MB) | attnb (100MB)
  u16* wq_bf = ws;
  u16* wp_bf = ws + 110592;
  u16* qkv1  = ws + 147456;                       // 4*576*65536 bf16 (NCHW)
  u16* attnb = qkv1 + (size_t)150994944;          // 4*65536*192 bf16 (flat)

  hipLaunchKernelGGL(k_wcvt,  dim3(432), dim3(256), 0, stream, wq, wpr, wq_bf, wp_bf);
  hipLaunchKernelGGL(k_qkv,   dim3(256, 4), dim3(768), 0, stream, x, wq_bf, qkv1);
  hipLaunchKernelGGL(k_dwmsa, dim3(1024, 4), dim3(512), 0, stream, qkv1, wdw, attnb);
  hipLaunchKernelGGL(k_proj,  dim3(256, 4), dim3(512), 0, stream, attnb, wp_bf, out);
}

// Round 17
// 448.457 us; speedup vs baseline: 1.0318x; 1.0318x over previous
//
#include <hip/hip_runtime.h>

typedef unsigned short u16;
typedef unsigned int   u32;
typedef __attribute__((ext_vector_type(8))) short s16x8;   // 8 x bf16 MFMA frag
typedef __attribute__((ext_vector_type(4))) float f32x4;

__device__ __forceinline__ u16 f2bf(float f) {
  u32 u = __builtin_bit_cast(u32, f);
  return (u16)((u + 0x7FFFu + ((u >> 16) & 1u)) >> 16);   // RNE
}
__device__ __forceinline__ float bf2f(u16 h) {
  return __builtin_bit_cast(float, (u32)h << 16);
}
__device__ __forceinline__ u32 pack2(float a, float b) {
  return (u32)f2bf(a) | ((u32)f2bf(b) << 16);
}

// ---------------- K0: weight f32 -> bf16 ----------------
__global__ __launch_bounds__(256) void k_wcvt(const float* __restrict__ wq,
                                              const float* __restrict__ wp,
                                              u16* __restrict__ wq_bf,
                                              u16* __restrict__ wp_bf) {
  int i = blockIdx.x * 256 + threadIdx.x;
  if (i < 576 * 192) wq_bf[i] = f2bf(wq[i]);
  if (i < 192 * 192) wp_bf[i] = f2bf(wp[i]);
}

// ---------------- K1: qkv 1x1 conv (GEMM M=576,K=192), W-in-registers ------
// (R14/R15-verified: swizzled LDS, 12 waves, wf once, zero barriers after gather.)
__global__ __launch_bounds__(768, 3) void k_qkv(const float* __restrict__ x,
                                                const u16* __restrict__ wq,
                                                u16* __restrict__ qkv1) {
  __shared__ __align__(16) u16 Xs[256 * 200];        // [n=256][k=192 pad 200]
  const int t  = threadIdx.x;
  const int b  = blockIdx.y;
  const int h1 = blockIdx.x;
  const float* xb = x + (size_t)b * 12582912;
  const int hbase = h1 >> 2;
  const int wbase = (h1 & 3) << 4;
#pragma unroll
  for (int it = 0; it < 8; ++it) {
    const int idx = it * 768 + t;          // 6144 units: f(4) x r(16) x c2(96)
    const int f = idx & 3;
    const int r = (idx >> 2) & 15;
    const int c = (idx >> 6) * 2;
    const int ho = ((r >> 2) & 3) * 64 + hbase;
    const int wo = (r & 3) * 64 + wbase + f * 4;
    const float* s0 = xb + (size_t)c * 65536 + (size_t)ho * 256 + wo;
    float4 v0 = *(const float4*)s0;
    float4 v1 = *(const float4*)(s0 + 65536);
    const int nb = 64 * f + r;
    const int slot = c >> 3;
    const int sl = (slot & 24) | ((slot + 2 * (r & 7)) & 7);
    const int ccol = sl * 8 + (c & 7);
    *(u32*)&Xs[(nb     ) * 200 + ccol] = pack2(v0.x, v1.x);
    *(u32*)&Xs[(nb + 16) * 200 + ccol] = pack2(v0.y, v1.y);
    *(u32*)&Xs[(nb + 32) * 200 + ccol] = pack2(v0.z, v1.z);
    *(u32*)&Xs[(nb + 48) * 200 + ccol] = pack2(v0.w, v1.w);
  }
  __syncthreads();
  const int lane = t & 63, wv = t >> 6;    // 12 waves, ch slice each
  const int lm = lane & 15, lk = lane >> 4;
  s16x8 wf[3][6];
#pragma unroll
  for (int mf = 0; mf < 3; ++mf) {
#pragma unroll
    for (int kk = 0; kk < 6; ++kk)
      wf[mf][kk] = *(const s16x8*)&wq[(size_t)(wv * 48 + mf * 16 + lm) * 192 + kk * 32 + lk * 8];
  }
  u16* const ob = qkv1 + (size_t)b * 37748736 + h1 * 256 + lk * 4;
  int slr[6];
#pragma unroll
  for (int kk = 0; kk < 6; ++kk) {
    const int slot = 4 * kk + lk;
    slr[kk] = ((slot & 24) | ((slot + 2 * (lm & 7)) & 7)) * 8;
  }

#pragma unroll 2
  for (int g = 0; g < 16; ++g) {
    s16x8 av[6];
#pragma unroll
    for (int kk = 0; kk < 6; ++kk)
      av[kk] = *(const s16x8*)&Xs[(g * 16 + lm) * 200 + slr[kk]];
    f32x4 acc[3];
#pragma unroll
    for (int mf = 0; mf < 3; ++mf) acc[mf] = f32x4{0.f, 0.f, 0.f, 0.f};
#pragma unroll
    for (int kk = 0; kk < 6; ++kk) {
#pragma unroll
      for (int mf = 0; mf < 3; ++mf)
        acc[mf] = __builtin_amdgcn_mfma_f32_16x16x32_bf16(av[kk], wf[mf][kk], acc[mf], 0, 0, 0);
    }
#pragma unroll
    for (int mf = 0; mf < 3; ++mf) {
      const int ch = wv * 48 + mf * 16 + lm;
      uint2 o;
      o.x = pack2(acc[mf][0], acc[mf][1]);
      o.y = pack2(acc[mf][2], acc[mf][3]);
      *(uint2*)(ob + (size_t)ch * 65536 + g * 16) = o;
    }
  }
}

// ---------------- K2: fused depthwise 3x3 + raw-reshape MSA ---------------
// R15-exact body; ONLY change: full unroll of the 9-octet loop so the
// compiler can hoist/interleave loads across octets itself (R16's manual
// struct pipeline constrained the scheduler and regressed). (512,4) caps
// VGPR at 128 = LDS-pinned occupancy preserved.
__global__ __launch_bounds__(512, 4) void k_dwmsa(const u16* __restrict__ qkv1,
                                                  const float* __restrict__ wdw,
                                                  u16* __restrict__ attnb) {
  __shared__ __align__(16) u16 Ds[2][18432];   // 73728 B
  const int t = threadIdx.x;
  const int b = blockIdx.y;
  const int gh = blockIdx.x >> 3;              // window-row 0..127
  const int c0 = (blockIdx.x & 7) * 32;        // col chunk
  const u16* qb = qkv1 + (size_t)b * 37748736;

  // ---- dw phase: 2 strips x 18432 outputs; thread -> 9 coalesced octets ----
  {
    const int s1 = t >> 8;                     // strip (0..1)
    const int tl = t & 255;
    const u32 F = 576u * (u32)((2 * gh + s1) * 256 + c0);
    const int ch0 = (int)(F >> 16);
    const int ch1 = (ch0 < 575) ? ch0 + 1 : 575;
    float wa[9], wb[9];
#pragma unroll
    for (int i = 0; i < 9; ++i) { wa[i] = wdw[ch0 * 9 + i]; wb[i] = wdw[ch1 * 9 + i]; }
#pragma unroll
    for (int k = 0; k < 9; ++k) {
      const int ii = (tl + 256 * k) * 8;       // lane-consecutive octets
      const u32 f = F + (u32)ii;
      const int ch = (int)(f >> 16);
      const int px = (int)(f & 65535u);
      const int h = px >> 8, w0 = px & 255;
      const u16* in = qb + ((size_t)ch << 16);
      const int hm = (h > 0) ? h - 1 : 0;
      const int hp = (h < 255) ? h + 1 : 255;
      const u16* rowm = in + (size_t)hm * 256 + w0;
      const u16* rowc = in + (size_t)h  * 256 + w0;
      const u16* rowp = in + (size_t)hp * 256 + w0;
      const int loff = (w0 > 0) ? -1 : 0;
      const int roff = (w0 < 248) ? 8 : 7;
      uint4 m0 = *(const uint4*)rowm;
      uint4 m1 = *(const uint4*)rowc;
      uint4 m2 = *(const uint4*)rowp;
      u16 lr0 = rowm[loff], rr0 = rowm[roff];
      u16 lr1 = rowc[loff], rr1 = rowc[roff];
      u16 lr2 = rowp[loff], rr2 = rowp[roff];
      const float vm = (h > 0)   ? 1.f : 0.f;
      const float vp = (h < 255) ? 1.f : 0.f;
      const float lmask = (w0 > 0) ? 1.f : 0.f;
      const float rmask = (w0 < 248) ? 1.f : 0.f;
      const bool sec = (ch != ch0);
      float w9[9];
#pragma unroll
      for (int i = 0; i < 9; ++i) w9[i] = sec ? wb[i] : wa[i];
      w9[0] *= vm; w9[1] *= vm; w9[2] *= vm;
      w9[6] *= vp; w9[7] *= vp; w9[8] *= vp;
      float acc[8] = {0.f,0.f,0.f,0.f,0.f,0.f,0.f,0.f};
      const uint4 mids[3] = {m0, m1, m2};
      const u16 lrs[3] = {lr0, lr1, lr2};
      const u16 rrs[3] = {rr0, rr1, rr2};
#pragma unroll
      for (int ky = 0; ky < 3; ++ky) {
        float e[10];
        e[0] = bf2f(lrs[ky]) * lmask;
        u32 uu[4] = {mids[ky].x, mids[ky].y, mids[ky].z, mids[ky].w};
#pragma unroll
        for (int q = 0; q < 4; ++q) {
          e[1 + 2 * q] = bf2f((u16)(uu[q] & 0xffffu));
          e[2 + 2 * q] = bf2f((u16)(uu[q] >> 16));
        }
        e[9] = bf2f(rrs[ky]) * rmask;
#pragma unroll
        for (int kx = 0; kx < 3; ++kx) {
          const float wk = w9[ky * 3 + kx];
#pragma unroll
          for (int jj = 0; jj < 8; ++jj) acc[jj] += wk * e[jj + kx];
        }
      }
      u32 o[4];
#pragma unroll
      for (int q = 0; q < 4; ++q)
        o[q] = pack2(acc[2 * q], acc[2 * q + 1]);
      *(uint4*)&Ds[s1][ii] = make_uint4(o[0], o[1], o[2], o[3]);
    }
  }
  __syncthreads();

  // ---- msa phase (R12/R13-verified) ----
  const int lc   = t & 3;
  const int head = (t >> 2) & 7;
  const int win  = t >> 5;                     // 0..15
  const int chq  = head * 24 + lc * 6;         // even
  float qv[4][6], kv[4][6], vv[4][6];
#pragma unroll
  for (int s1 = 0; s1 < 2; ++s1) {
#pragma unroll
    for (int s2 = 0; s2 < 2; ++s2) {
      const int tt = s1 * 2 + s2;
      const int base = (2 * win + s2) * 576 + chq;
#pragma unroll
      for (int pp = 0; pp < 3; ++pp) {
        u32 aq = *(const u32*)&Ds[s1][base + 2 * pp];
        u32 ak = *(const u32*)&Ds[s1][base + 192 + 2 * pp];
        u32 av = *(const u32*)&Ds[s1][base + 384 + 2 * pp];
        qv[tt][2 * pp]     = bf2f((u16)(aq & 0xffffu));
        qv[tt][2 * pp + 1] = bf2f((u16)(aq >> 16));
        kv[tt][2 * pp]     = bf2f((u16)(ak & 0xffffu));
        kv[tt][2 * pp + 1] = bf2f((u16)(ak >> 16));
        vv[tt][2 * pp]     = bf2f((u16)(av & 0xffffu));
        vv[tt][2 * pp + 1] = bf2f((u16)(av >> 16));
      }
    }
  }
  float s[4][4];
#pragma unroll
  for (int tq = 0; tq < 4; ++tq) {
#pragma unroll
    for (int tk = 0; tk < 4; ++tk) {
      float d = 0.f;
#pragma unroll
      for (int dd = 0; dd < 6; ++dd) d += qv[tq][dd] * kv[tk][dd];
      d += __shfl_xor(d, 1);
      d += __shfl_xor(d, 2);
      s[tq][tk] = d * 0.35355339059327373f;    // SCALE = HEADS^-0.5
    }
  }
  u16* const ab = attnb + (size_t)b * 12582912;
#pragma unroll
  for (int tq = 0; tq < 4; ++tq) {
    float mx = fmaxf(fmaxf(s[tq][0], s[tq][1]), fmaxf(s[tq][2], s[tq][3]));
    float e0 = __expf(s[tq][0] - mx), e1 = __expf(s[tq][1] - mx);
    float e2 = __expf(s[tq][2] - mx), e3 = __expf(s[tq][3] - mx);
    float inv = 1.f / (e0 + e1 + e2 + e3);
    float a0 = e0 * inv, a1 = e1 * inv, a2 = e2 * inv, a3 = e3 * inv;
    float o6[6];
#pragma unroll
    for (int dd = 0; dd < 6; ++dd)
      o6[dd] = a0 * vv[0][dd] + a1 * vv[1][dd] + a2 * vv[2][dd] + a3 * vv[3][dd];
    const int s1 = tq >> 1, s2 = tq & 1;
    const size_t pg = (size_t)((2 * gh + s1) * 256) + c0 + 2 * win + s2;
    u16* dst = ab + pg * 192 + chq;
    *(u32*)(dst)     = pack2(o6[0], o6[1]);
    *(u32*)(dst + 2) = pack2(o6[2], o6[3]);
    *(u32*)(dst + 4) = pack2(o6[4], o6[5]);
  }
}

// ---------------- K4: proj 1x1 (GEMM M=192,K=192) + shuffle_back ----------
// (R14-verified: barrier-free direct scatter, swizzled LDS.)
__global__ __launch_bounds__(512) void k_proj(const u16* __restrict__ attnb,
                                              const u16* __restrict__ wp,
                                              float* __restrict__ out) {
  __shared__ __align__(16) u16 Xs[256 * 200];
  const int t  = threadIdx.x;
  const int b  = blockIdx.y;
  const int hs = blockIdx.x;
  const int pix = t & 255, cg = t >> 8;
  {
    const u16* ab = attnb + (size_t)b * 12582912 + (size_t)hs * 256 + pix;
    u16* xrow = &Xs[pix * 200];
    const int key = (pix >> 4) & 7;
#pragma unroll 8
    for (int i = 0; i < 96; i += 2) {
      const int c = cg * 96 + i;
      const int slot = c >> 3;
      const int sl = (slot & 24) | ((slot + key) & 7);
      u16 v0 = ab[(size_t)c * 65536];
      u16 v1 = ab[(size_t)(c + 1) * 65536];
      *(u32*)&xrow[sl * 8 + (c & 7)] = (u32)v0 | ((u32)v1 << 16);
    }
  }
  __syncthreads();
  const int lane = t & 63, wid = t >> 6;
  const int lm = lane & 15, lk = lane >> 4;
  s16x8 bv[2][6];
#pragma unroll
  for (int rp = 0; rp < 2; ++rp) {
    const int r = 2 * wid + rp;
#pragma unroll
    for (int kk = 0; kk < 6; ++kk) {
      const int slot = 4 * kk + lk;
      const int sl = (slot & 24) | ((slot + (lm & 7)) & 7);
      bv[rp][kk] = *(const s16x8*)&Xs[(16 * lm + r) * 200 + sl * 8];
    }
  }
  float* const ob = out + (size_t)b * 12582912;
  const int hq_base = hs >> 2;
  const int wq_base = (hs & 3) << 4;
  int hqr[2], wq0[2];
#pragma unroll
  for (int rp = 0; rp < 2; ++rp) {
    const int r = 2 * wid + rp;
    hqr[rp] = ((r >> 2) & 3) * 64 + hq_base;
    wq0[rp] = (r & 3) * 64 + wq_base;
  }

#pragma unroll 1
  for (int mt = 0; mt < 3; ++mt) {
    f32x4 acc[4][2];
#pragma unroll
    for (int i = 0; i < 4; ++i) {
      acc[i][0] = f32x4{0.f, 0.f, 0.f, 0.f};
      acc[i][1] = f32x4{0.f, 0.f, 0.f, 0.f};
    }
#pragma unroll
    for (int kk = 0; kk < 6; ++kk) {
      s16x8 af[4];
#pragma unroll
      for (int mf = 0; mf < 4; ++mf)
        af[mf] = *(const s16x8*)&wp[(size_t)(mt * 64 + mf * 16 + lm) * 192 + kk * 32 + lk * 8];
#pragma unroll
      for (int mf = 0; mf < 4; ++mf) {
#pragma unroll
        for (int rp = 0; rp < 2; ++rp)
          acc[mf][rp] = __builtin_amdgcn_mfma_f32_16x16x32_bf16(af[mf], bv[rp][kk], acc[mf][rp], 0, 0, 0);
      }
    }
#pragma unroll
    for (int mf = 0; mf < 4; ++mf) {
#pragma unroll
      for (int rp = 0; rp < 2; ++rp) {
        float* base = ob + (size_t)(mt * 64 + mf * 16 + lk * 4) * 65536
                         + (size_t)hqr[rp] * 256 + wq0[rp] + lm;
#pragma unroll
        for (int rr = 0; rr < 4; ++rr)
          base[(size_t)rr * 65536] = acc[mf][rp][rr];
      }
    }
  }
}

extern "C" void kernel_launch(void* const* d_in, const int* in_sizes, int n_in,
                              void* d_out, int out_size, void* d_ws, size_t ws_size,
                              hipStream_t stream) {
  const float* x   = (const float*)d_in[0];
  const float* wq  = (const float*)d_in[1];
  const float* wdw = (const float*)d_in[2];
  const float* wpr = (const float*)d_in[3];
  float* out = (float*)d_out;
  u16* ws = (u16*)d_ws;
  // layout (u16): wq_bf | wp_bf | qkv1 (302MB) | attnb (100MB)
  u16* wq_bf = ws;
  u16* wp_bf = ws + 110592;
  u16* qkv1  = ws + 147456;                       // 4*576*65536 bf16 (NCHW)
  u16* attnb = qkv1 + (size_t)150994944;          // 4*65536*192 bf16 (flat)

  hipLaunchKernelGGL(k_wcvt,  dim3(432), dim3(256), 0, stream, wq, wpr, wq_bf, wp_bf);
  hipLaunchKernelGGL(k_qkv,   dim3(256, 4), dim3(768), 0, stream, x, wq_bf, qkv1);
  hipLaunchKernelGGL(k_dwmsa, dim3(1024, 4), dim3(512), 0, stream, qkv1, wdw, attnb);
  hipLaunchKernelGGL(k_proj,  dim3(256, 4), dim3(512), 0, stream, attnb, wp_bf, out);
}

// Round 19
// 441.498 us; speedup vs baseline: 1.0481x; 1.0158x over previous
//
#include <hip/hip_runtime.h>
#include <hip/hip_bf16.h>

typedef unsigned short u16;
typedef unsigned int   u32;
typedef __attribute__((ext_vector_type(8))) short s16x8;   // 8 x bf16 MFMA frag
typedef __attribute__((ext_vector_type(4))) float f32x4;

__device__ __forceinline__ u16 f2bf(float f) {
  u32 u = __builtin_bit_cast(u32, f);
  return (u16)((u + 0x7FFFu + ((u >> 16) & 1u)) >> 16);   // RNE
}
__device__ __forceinline__ float bf2f(u16 h) {
  return __builtin_bit_cast(float, (u32)h << 16);
}
// Packed f32x2 -> bf16x2 via the official cast path; compiler folds this to
// a single v_cvt_pk_bf16_f32 (vs ~10 VALU ops for the hand-rolled RNE pair).
// (__hip_bfloat162 isn't trivially copyable -> memcpy instead of bit_cast;
// clang folds the 4-byte memcpy to a register move.)
__device__ __forceinline__ u32 pack2(float a, float b) {
  __hip_bfloat162 h = __float22bfloat162_rn(make_float2(a, b));
  u32 r;
  __builtin_memcpy(&r, &h, 4);
  return r;
}

// ---------------- K0: weight f32 -> bf16 ----------------
__global__ __launch_bounds__(256) void k_wcvt(const float* __restrict__ wq,
                                              const float* __restrict__ wp,
                                              u16* __restrict__ wq_bf,
                                              u16* __restrict__ wp_bf) {
  int i = blockIdx.x * 256 + threadIdx.x;
  if (i < 576 * 192) wq_bf[i] = f2bf(wq[i]);
  if (i < 192 * 192) wp_bf[i] = f2bf(wp[i]);
}

// ---------------- K1: qkv 1x1 conv (GEMM M=576,K=192), W-in-registers ------
// (R14/R15-verified: swizzled LDS, 12 waves, wf once, zero barriers after gather.)
__global__ __launch_bounds__(768, 3) void k_qkv(const float* __restrict__ x,
                                                const u16* __restrict__ wq,
                                                u16* __restrict__ qkv1) {
  __shared__ __align__(16) u16 Xs[256 * 200];        // [n=256][k=192 pad 200]
  const int t  = threadIdx.x;
  const int b  = blockIdx.y;
  const int h1 = blockIdx.x;
  const float* xb = x + (size_t)b * 12582912;
  const int hbase = h1 >> 2;
  const int wbase = (h1 & 3) << 4;
#pragma unroll
  for (int it = 0; it < 8; ++it) {
    const int idx = it * 768 + t;          // 6144 units: f(4) x r(16) x c2(96)
    const int f = idx & 3;
    const int r = (idx >> 2) & 15;
    const int c = (idx >> 6) * 2;
    const int ho = ((r >> 2) & 3) * 64 + hbase;
    const int wo = (r & 3) * 64 + wbase + f * 4;
    const float* s0 = xb + (size_t)c * 65536 + (size_t)ho * 256 + wo;
    float4 v0 = *(const float4*)s0;
    float4 v1 = *(const float4*)(s0 + 65536);
    const int nb = 64 * f + r;
    const int slot = c >> 3;
    const int sl = (slot & 24) | ((slot + 2 * (r & 7)) & 7);
    const int ccol = sl * 8 + (c & 7);
    *(u32*)&Xs[(nb     ) * 200 + ccol] = pack2(v0.x, v1.x);
    *(u32*)&Xs[(nb + 16) * 200 + ccol] = pack2(v0.y, v1.y);
    *(u32*)&Xs[(nb + 32) * 200 + ccol] = pack2(v0.z, v1.z);
    *(u32*)&Xs[(nb + 48) * 200 + ccol] = pack2(v0.w, v1.w);
  }
  __syncthreads();
  const int lane = t & 63, wv = t >> 6;    // 12 waves, ch slice each
  const int lm = lane & 15, lk = lane >> 4;
  s16x8 wf[3][6];
#pragma unroll
  for (int mf = 0; mf < 3; ++mf) {
#pragma unroll
    for (int kk = 0; kk < 6; ++kk)
      wf[mf][kk] = *(const s16x8*)&wq[(size_t)(wv * 48 + mf * 16 + lm) * 192 + kk * 32 + lk * 8];
  }
  u16* const ob = qkv1 + (size_t)b * 37748736 + h1 * 256 + lk * 4;
  int slr[6];
#pragma unroll
  for (int kk = 0; kk < 6; ++kk) {
    const int slot = 4 * kk + lk;
    slr[kk] = ((slot & 24) | ((slot + 2 * (lm & 7)) & 7)) * 8;
  }

#pragma unroll 2
  for (int g = 0; g < 16; ++g) {
    s16x8 av[6];
#pragma unroll
    for (int kk = 0; kk < 6; ++kk)
      av[kk] = *(const s16x8*)&Xs[(g * 16 + lm) * 200 + slr[kk]];
    f32x4 acc[3];
#pragma unroll
    for (int mf = 0; mf < 3; ++mf) acc[mf] = f32x4{0.f, 0.f, 0.f, 0.f};
#pragma unroll
    for (int kk = 0; kk < 6; ++kk) {
#pragma unroll
      for (int mf = 0; mf < 3; ++mf)
        acc[mf] = __builtin_amdgcn_mfma_f32_16x16x32_bf16(av[kk], wf[mf][kk], acc[mf], 0, 0, 0);
    }
#pragma unroll
    for (int mf = 0; mf < 3; ++mf) {
      const int ch = wv * 48 + mf * 16 + lm;
      uint2 o;
      o.x = pack2(acc[mf][0], acc[mf][1]);
      o.y = pack2(acc[mf][2], acc[mf][3]);
      *(uint2*)(ob + (size_t)ch * 65536 + g * 16) = o;
    }
  }
}

// ---------------- K2: fused depthwise 3x3 + raw-reshape MSA ---------------
// R15-exact structure (best measured); only pack2's implementation changed.
__global__ __launch_bounds__(512, 2) void k_dwmsa(const u16* __restrict__ qkv1,
                                                  const float* __restrict__ wdw,
                                                  u16* __restrict__ attnb) {
  __shared__ __align__(16) u16 Ds[2][18432];   // 73728 B
  const int t = threadIdx.x;
  const int b = blockIdx.y;
  const int gh = blockIdx.x >> 3;              // window-row 0..127
  const int c0 = (blockIdx.x & 7) * 32;        // col chunk
  const u16* qb = qkv1 + (size_t)b * 37748736;

  // ---- dw phase: 2 strips x 18432 outputs; thread -> 9 coalesced octets ----
  {
    const int s1 = t >> 8;                     // strip (0..1)
    const int tl = t & 255;
    const u32 F = 576u * (u32)((2 * gh + s1) * 256 + c0);
    const int ch0 = (int)(F >> 16);
    const int ch1 = (ch0 < 575) ? ch0 + 1 : 575;
    float wa[9], wb[9];
#pragma unroll
    for (int i = 0; i < 9; ++i) { wa[i] = wdw[ch0 * 9 + i]; wb[i] = wdw[ch1 * 9 + i]; }
#pragma unroll 3
    for (int k = 0; k < 9; ++k) {
      const int ii = (tl + 256 * k) * 8;       // lane-consecutive octets
      const u32 f = F + (u32)ii;
      const int ch = (int)(f >> 16);
      const int px = (int)(f & 65535u);
      const int h = px >> 8, w0 = px & 255;
      const u16* in = qb + ((size_t)ch << 16);
      const int hm = (h > 0) ? h - 1 : 0;
      const int hp = (h < 255) ? h + 1 : 255;
      const u16* rowm = in + (size_t)hm * 256 + w0;
      const u16* rowc = in + (size_t)h  * 256 + w0;
      const u16* rowp = in + (size_t)hp * 256 + w0;
      const int loff = (w0 > 0) ? -1 : 0;
      const int roff = (w0 < 248) ? 8 : 7;
      uint4 m0 = *(const uint4*)rowm;
      uint4 m1 = *(const uint4*)rowc;
      uint4 m2 = *(const uint4*)rowp;
      u16 lr0 = rowm[loff], rr0 = rowm[roff];
      u16 lr1 = rowc[loff], rr1 = rowc[roff];
      u16 lr2 = rowp[loff], rr2 = rowp[roff];
      const float vm = (h > 0)   ? 1.f : 0.f;
      const float vp = (h < 255) ? 1.f : 0.f;
      const float lmask = (w0 > 0) ? 1.f : 0.f;
      const float rmask = (w0 < 248) ? 1.f : 0.f;
      const bool sec = (ch != ch0);
      float w9[9];
#pragma unroll
      for (int i = 0; i < 9; ++i) w9[i] = sec ? wb[i] : wa[i];
      w9[0] *= vm; w9[1] *= vm; w9[2] *= vm;
      w9[6] *= vp; w9[7] *= vp; w9[8] *= vp;
      float acc[8] = {0.f,0.f,0.f,0.f,0.f,0.f,0.f,0.f};
      const uint4 mids[3] = {m0, m1, m2};
      const u16 lrs[3] = {lr0, lr1, lr2};
      const u16 rrs[3] = {rr0, rr1, rr2};
#pragma unroll
      for (int ky = 0; ky < 3; ++ky) {
        float e[10];
        e[0] = bf2f(lrs[ky]) * lmask;
        u32 uu[4] = {mids[ky].x, mids[ky].y, mids[ky].z, mids[ky].w};
#pragma unroll
        for (int q = 0; q < 4; ++q) {
          e[1 + 2 * q] = bf2f((u16)(uu[q] & 0xffffu));
          e[2 + 2 * q] = bf2f((u16)(uu[q] >> 16));
        }
        e[9] = bf2f(rrs[ky]) * rmask;
#pragma unroll
        for (int kx = 0; kx < 3; ++kx) {
          const float wk = w9[ky * 3 + kx];
#pragma unroll
          for (int jj = 0; jj < 8; ++jj) acc[jj] += wk * e[jj + kx];
        }
      }
      u32 o[4];
#pragma unroll
      for (int q = 0; q < 4; ++q)
        o[q] = pack2(acc[2 * q], acc[2 * q + 1]);
      *(uint4*)&Ds[s1][ii] = make_uint4(o[0], o[1], o[2], o[3]);
    }
  }
  __syncthreads();

  // ---- msa phase (R12/R13-verified) ----
  const int lc   = t & 3;
  const int head = (t >> 2) & 7;
  const int win  = t >> 5;                     // 0..15
  const int chq  = head * 24 + lc * 6;         // even
  float qv[4][6], kv[4][6], vv[4][6];
#pragma unroll
  for (int s1 = 0; s1 < 2; ++s1) {
#pragma unroll
    for (int s2 = 0; s2 < 2; ++s2) {
      const int tt = s1 * 2 + s2;
      const int base = (2 * win + s2) * 576 + chq;
#pragma unroll
      for (int pp = 0; pp < 3; ++pp) {
        u32 aq = *(const u32*)&Ds[s1][base + 2 * pp];
        u32 ak = *(const u32*)&Ds[s1][base + 192 + 2 * pp];
        u32 av = *(const u32*)&Ds[s1][base + 384 + 2 * pp];
        qv[tt][2 * pp]     = bf2f((u16)(aq & 0xffffu));
        qv[tt][2 * pp + 1] = bf2f((u16)(aq >> 16));
        kv[tt][2 * pp]     = bf2f((u16)(ak & 0xffffu));
        kv[tt][2 * pp + 1] = bf2f((u16)(ak >> 16));
        vv[tt][2 * pp]     = bf2f((u16)(av & 0xffffu));
        vv[tt][2 * pp + 1] = bf2f((u16)(av >> 16));
      }
    }
  }
  float s[4][4];
#pragma unroll
  for (int tq = 0; tq < 4; ++tq) {
#pragma unroll
    for (int tk = 0; tk < 4; ++tk) {
      float d = 0.f;
#pragma unroll
      for (int dd = 0; dd < 6; ++dd) d += qv[tq][dd] * kv[tk][dd];
      d += __shfl_xor(d, 1);
      d += __shfl_xor(d, 2);
      s[tq][tk] = d * 0.35355339059327373f;    // SCALE = HEADS^-0.5
    }
  }
  u16* const ab = attnb + (size_t)b * 12582912;
#pragma unroll
  for (int tq = 0; tq < 4; ++tq) {
    float mx = fmaxf(fmaxf(s[tq][0], s[tq][1]), fmaxf(s[tq][2], s[tq][3]));
    float e0 = __expf(s[tq][0] - mx), e1 = __expf(s[tq][1] - mx);
    float e2 = __expf(s[tq][2] - mx), e3 = __expf(s[tq][3] - mx);
    float inv = 1.f / (e0 + e1 + e2 + e3);
    float a0 = e0 * inv, a1 = e1 * inv, a2 = e2 * inv, a3 = e3 * inv;
    float o6[6];
#pragma unroll
    for (int dd = 0; dd < 6; ++dd)
      o6[dd] = a0 * vv[0][dd] + a1 * vv[1][dd] + a2 * vv[2][dd] + a3 * vv[3][dd];
    const int s1 = tq >> 1, s2 = tq & 1;
    const size_t pg = (size_t)((2 * gh + s1) * 256) + c0 + 2 * win + s2;
    u16* dst = ab + pg * 192 + chq;
    *(u32*)(dst)     = pack2(o6[0], o6[1]);
    *(u32*)(dst + 2) = pack2(o6[2], o6[3]);
    *(u32*)(dst + 4) = pack2(o6[4], o6[5]);
  }
}

// ---------------- K4: proj 1x1 (GEMM M=192,K=192) + shuffle_back ----------
// (R14-verified: barrier-free direct scatter, swizzled LDS.)
__global__ __launch_bounds__(512) void k_proj(const u16* __restrict__ attnb,
                                              const u16* __restrict__ wp,
                                              float* __restrict__ out) {
  __shared__ __align__(16) u16 Xs[256 * 200];
  const int t  = threadIdx.x;
  const int b  = blockIdx.y;
  const int hs = blockIdx.x;
  const int pix = t & 255, cg = t >> 8;
  {
    const u16* ab = attnb + (size_t)b * 12582912 + (size_t)hs * 256 + pix;
    u16* xrow = &Xs[pix * 200];
    const int key = (pix >> 4) & 7;
#pragma unroll 8
    for (int i = 0; i < 96; i += 2) {
      const int c = cg * 96 + i;
      const int slot = c >> 3;
      const int sl = (slot & 24) | ((slot + key) & 7);
      u16 v0 = ab[(size_t)c * 65536];
      u16 v1 = ab[(size_t)(c + 1) * 65536];
      *(u32*)&xrow[sl * 8 + (c & 7)] = (u32)v0 | ((u32)v1 << 16);
    }
  }
  __syncthreads();
  const int lane = t & 63, wid = t >> 6;
  const int lm = lane & 15, lk = lane >> 4;
  s16x8 bv[2][6];
#pragma unroll
  for (int rp = 0; rp < 2; ++rp) {
    const int r = 2 * wid + rp;
#pragma unroll
    for (int kk = 0; kk < 6; ++kk) {
      const int slot = 4 * kk + lk;
      const int sl = (slot & 24) | ((slot + (lm & 7)) & 7);
      bv[rp][kk] = *(const s16x8*)&Xs[(16 * lm + r) * 200 + sl * 8];
    }
  }
  float* const ob = out + (size_t)b * 12582912;
  const int hq_base = hs >> 2;
  const int wq_base = (hs & 3) << 4;
  int hqr[2], wq0[2];
#pragma unroll
  for (int rp = 0; rp < 2; ++rp) {
    const int r = 2 * wid + rp;
    hqr[rp] = ((r >> 2) & 3) * 64 + hq_base;
    wq0[rp] = (r & 3) * 64 + wq_base;
  }

#pragma unroll 1
  for (int mt = 0; mt < 3; ++mt) {
    f32x4 acc[4][2];
#pragma unroll
    for (int i = 0; i < 4; ++i) {
      acc[i][0] = f32x4{0.f, 0.f, 0.f, 0.f};
      acc[i][1] = f32x4{0.f, 0.f, 0.f, 0.f};
    }
#pragma unroll
    for (int kk = 0; kk < 6; ++kk) {
      s16x8 af[4];
#pragma unroll
      for (int mf = 0; mf < 4; ++mf)
        af[mf] = *(const s16x8*)&wp[(size_t)(mt * 64 + mf * 16 + lm) * 192 + kk * 32 + lk * 8];
#pragma unroll
      for (int mf = 0; mf < 4; ++mf) {
#pragma unroll
        for (int rp = 0; rp < 2; ++rp)
          acc[mf][rp] = __builtin_amdgcn_mfma_f32_16x16x32_bf16(af[mf], bv[rp][kk], acc[mf][rp], 0, 0, 0);
      }
    }
#pragma unroll
    for (int mf = 0; mf < 4; ++mf) {
#pragma unroll
      for (int rp = 0; rp < 2; ++rp) {
        float* base = ob + (size_t)(mt * 64 + mf * 16 + lk * 4) * 65536
                         + (size_t)hqr[rp] * 256 + wq0[rp] + lm;
#pragma unroll
        for (int rr = 0; rr < 4; ++rr)
          base[(size_t)rr * 65536] = acc[mf][rp][rr];
      }
    }
  }
}

extern "C" void kernel_launch(void* const* d_in, const int* in_sizes, int n_in,
                              void* d_out, int out_size, void* d_ws, size_t ws_size,
                              hipStream_t stream) {
  const float* x   = (const float*)d_in[0];
  const float* wq  = (const float*)d_in[1];
  const float* wdw = (const float*)d_in[2];
  const float* wpr = (const float*)d_in[3];
  float* out = (float*)d_out;
  u16* ws = (u16*)d_ws;
  // layout (u16): wq_bf | wp_bf | qkv1 (302MB) | attnb (100MB)
  u16* wq_bf = ws;
  u16* wp_bf = ws + 110592;
  u16* qkv1  = ws + 147456;                       // 4*576*65536 bf16 (NCHW)
  u16* attnb = qkv1 + (size_t)150994944;          // 4*65536*192 bf16 (flat)

  hipLaunchKernelGGL(k_wcvt,  dim3(432), dim3(256), 0, stream, wq, wpr, wq_bf, wp_bf);
  hipLaunchKernelGGL(k_qkv,   dim3(256, 4), dim3(768), 0, stream, x, wq_bf, qkv1);
  hipLaunchKernelGGL(k_dwmsa, dim3(1024, 4), dim3(512), 0, stream, qkv1, wdw, attnb);
  hipLaunchKernelGGL(k_proj,  dim3(256, 4), dim3(512), 0, stream, attnb, wp_bf, out);
}

// Round 20
// 397.451 us; speedup vs baseline: 1.1642x; 1.1108x over previous
//
#include <hip/hip_runtime.h>
#include <hip/hip_bf16.h>

typedef unsigned short u16;
typedef unsigned int   u32;
typedef __attribute__((ext_vector_type(8))) short s16x8;   // 8 x bf16 MFMA frag
typedef __attribute__((ext_vector_type(4))) float f32x4;

__device__ __forceinline__ u16 f2bf(float f) {
  u32 u = __builtin_bit_cast(u32, f);
  return (u16)((u + 0x7FFFu + ((u >> 16) & 1u)) >> 16);   // RNE
}
__device__ __forceinline__ float bf2f(u16 h) {
  return __builtin_bit_cast(float, (u32)h << 16);
}
// Packed f32x2 -> bf16x2; folds to v_cvt_pk_bf16_f32.
__device__ __forceinline__ u32 pack2(float a, float b) {
  __hip_bfloat162 h = __float22bfloat162_rn(make_float2(a, b));
  u32 r;
  __builtin_memcpy(&r, &h, 4);
  return r;
}

// ---------------- K0: weight f32 -> bf16 ----------------
__global__ __launch_bounds__(256) void k_wcvt(const float* __restrict__ wq,
                                              const float* __restrict__ wp,
                                              u16* __restrict__ wq_bf,
                                              u16* __restrict__ wp_bf) {
  int i = blockIdx.x * 256 + threadIdx.x;
  if (i < 576 * 192) wq_bf[i] = f2bf(wq[i]);
  if (i < 192 * 192) wp_bf[i] = f2bf(wp[i]);
}

// ---------------- K1: qkv 1x1 conv (GEMM M=576,K=192), W-in-registers ------
// (R14/R15-verified: swizzled LDS, 12 waves, wf once, zero barriers after gather.)
__global__ __launch_bounds__(768, 3) void k_qkv(const float* __restrict__ x,
                                                const u16* __restrict__ wq,
                                                u16* __restrict__ qkv1) {
  __shared__ __align__(16) u16 Xs[256 * 200];        // [n=256][k=192 pad 200]
  const int t  = threadIdx.x;
  const int b  = blockIdx.y;
  const int h1 = blockIdx.x;
  const float* xb = x + (size_t)b * 12582912;
  const int hbase = h1 >> 2;
  const int wbase = (h1 & 3) << 4;
#pragma unroll
  for (int it = 0; it < 8; ++it) {
    const int idx = it * 768 + t;          // 6144 units: f(4) x r(16) x c2(96)
    const int f = idx & 3;
    const int r = (idx >> 2) & 15;
    const int c = (idx >> 6) * 2;
    const int ho = ((r >> 2) & 3) * 64 + hbase;
    const int wo = (r & 3) * 64 + wbase + f * 4;
    const float* s0 = xb + (size_t)c * 65536 + (size_t)ho * 256 + wo;
    float4 v0 = *(const float4*)s0;
    float4 v1 = *(const float4*)(s0 + 65536);
    const int nb = 64 * f + r;
    const int slot = c >> 3;
    const int sl = (slot & 24) | ((slot + 2 * (r & 7)) & 7);
    const int ccol = sl * 8 + (c & 7);
    *(u32*)&Xs[(nb     ) * 200 + ccol] = pack2(v0.x, v1.x);
    *(u32*)&Xs[(nb + 16) * 200 + ccol] = pack2(v0.y, v1.y);
    *(u32*)&Xs[(nb + 32) * 200 + ccol] = pack2(v0.z, v1.z);
    *(u32*)&Xs[(nb + 48) * 200 + ccol] = pack2(v0.w, v1.w);
  }
  __syncthreads();
  const int lane = t & 63, wv = t >> 6;    // 12 waves, ch slice each
  const int lm = lane & 15, lk = lane >> 4;
  s16x8 wf[3][6];
#pragma unroll
  for (int mf = 0; mf < 3; ++mf) {
#pragma unroll
    for (int kk = 0; kk < 6; ++kk)
      wf[mf][kk] = *(const s16x8*)&wq[(size_t)(wv * 48 + mf * 16 + lm) * 192 + kk * 32 + lk * 8];
  }
  u16* const ob = qkv1 + (size_t)b * 37748736 + h1 * 256 + lk * 4;
  int slr[6];
#pragma unroll
  for (int kk = 0; kk < 6; ++kk) {
    const int slot = 4 * kk + lk;
    slr[kk] = ((slot & 24) | ((slot + 2 * (lm & 7)) & 7)) * 8;
  }

#pragma unroll 2
  for (int g = 0; g < 16; ++g) {
    s16x8 av[6];
#pragma unroll
    for (int kk = 0; kk < 6; ++kk)
      av[kk] = *(const s16x8*)&Xs[(g * 16 + lm) * 200 + slr[kk]];
    f32x4 acc[3];
#pragma unroll
    for (int mf = 0; mf < 3; ++mf) acc[mf] = f32x4{0.f, 0.f, 0.f, 0.f};
#pragma unroll
    for (int kk = 0; kk < 6; ++kk) {
#pragma unroll
      for (int mf = 0; mf < 3; ++mf)
        acc[mf] = __builtin_amdgcn_mfma_f32_16x16x32_bf16(av[kk], wf[mf][kk], acc[mf], 0, 0, 0);
    }
#pragma unroll
    for (int mf = 0; mf < 3; ++mf) {
      const int ch = wv * 48 + mf * 16 + lm;
      uint2 o;
      o.x = pack2(acc[mf][0], acc[mf][1]);
      o.y = pack2(acc[mf][2], acc[mf][3]);
      *(uint2*)(ob + (size_t)ch * 65536 + g * 16) = o;
    }
  }
}

// ---------------- K2: fused depthwise 3x3 + raw-reshape MSA ---------------
// R19 structure; edge loads replaced by cross-lane shuffles: octets are
// lane-consecutive along the flat strip, so e[0] = prev lane's hi(m.w) and
// e[9] = next lane's lo(m.x). All boundary lanes (wave edges, row crossings)
// already have lmask/rmask = 0 (64 lanes x 8px = exactly 2 rows). Cuts
// per-thread VMEM instrs 99 -> 45.
__global__ __launch_bounds__(512, 2) void k_dwmsa(const u16* __restrict__ qkv1,
                                                  const float* __restrict__ wdw,
                                                  u16* __restrict__ attnb) {
  __shared__ __align__(16) u16 Ds[2][18432];   // 73728 B
  const int t = threadIdx.x;
  const int b = blockIdx.y;
  const int gh = blockIdx.x >> 3;              // window-row 0..127
  const int c0 = (blockIdx.x & 7) * 32;        // col chunk
  const u16* qb = qkv1 + (size_t)b * 37748736;

  // ---- dw phase: 2 strips x 18432 outputs; thread -> 9 coalesced octets ----
  {
    const int s1 = t >> 8;                     // strip (0..1)
    const int tl = t & 255;
    const int lane = t & 63;
    const u32 F = 576u * (u32)((2 * gh + s1) * 256 + c0);
    const int ch0 = (int)(F >> 16);
    const int ch1 = (ch0 < 575) ? ch0 + 1 : 575;
    float wa[9], wb[9];
#pragma unroll
    for (int i = 0; i < 9; ++i) { wa[i] = wdw[ch0 * 9 + i]; wb[i] = wdw[ch1 * 9 + i]; }
#pragma unroll 3
    for (int k = 0; k < 9; ++k) {
      const int ii = (tl + 256 * k) * 8;       // lane-consecutive octets
      const u32 f = F + (u32)ii;
      const int ch = (int)(f >> 16);
      const int px = (int)(f & 65535u);
      const int h = px >> 8, w0 = px & 255;
      const u16* in = qb + ((size_t)ch << 16);
      const int hm = (h > 0) ? h - 1 : 0;
      const int hp = (h < 255) ? h + 1 : 255;
      uint4 m0 = *(const uint4*)(in + (size_t)hm * 256 + w0);
      uint4 m1 = *(const uint4*)(in + (size_t)h  * 256 + w0);
      uint4 m2 = *(const uint4*)(in + (size_t)hp * 256 + w0);
      // edges via cross-lane shuffle (boundary lanes masked below)
      u32 p0 = (u32)__shfl((int)m0.w, lane - 1);
      u32 p1 = (u32)__shfl((int)m1.w, lane - 1);
      u32 p2 = (u32)__shfl((int)m2.w, lane - 1);
      u32 n0 = (u32)__shfl((int)m0.x, lane + 1);
      u32 n1 = (u32)__shfl((int)m1.x, lane + 1);
      u32 n2 = (u32)__shfl((int)m2.x, lane + 1);
      const float vm = (h > 0)   ? 1.f : 0.f;
      const float vp = (h < 255) ? 1.f : 0.f;
      const float lmask = (w0 > 0) ? 1.f : 0.f;
      const float rmask = (w0 < 248) ? 1.f : 0.f;
      const bool sec = (ch != ch0);
      float w9[9];
#pragma unroll
      for (int i = 0; i < 9; ++i) w9[i] = sec ? wb[i] : wa[i];
      w9[0] *= vm; w9[1] *= vm; w9[2] *= vm;
      w9[6] *= vp; w9[7] *= vp; w9[8] *= vp;
      float acc[8] = {0.f,0.f,0.f,0.f,0.f,0.f,0.f,0.f};
      const uint4 mids[3] = {m0, m1, m2};
      const u32 prevs[3] = {p0, p1, p2};
      const u32 nexts[3] = {n0, n1, n2};
#pragma unroll
      for (int ky = 0; ky < 3; ++ky) {
        float e[10];
        e[0] = bf2f((u16)(prevs[ky] >> 16)) * lmask;
        u32 uu[4] = {mids[ky].x, mids[ky].y, mids[ky].z, mids[ky].w};
#pragma unroll
        for (int q = 0; q < 4; ++q) {
          e[1 + 2 * q] = bf2f((u16)(uu[q] & 0xffffu));
          e[2 + 2 * q] = bf2f((u16)(uu[q] >> 16));
        }
        e[9] = bf2f((u16)(nexts[ky] & 0xffffu)) * rmask;
#pragma unroll
        for (int kx = 0; kx < 3; ++kx) {
          const float wk = w9[ky * 3 + kx];
#pragma unroll
          for (int jj = 0; jj < 8; ++jj) acc[jj] += wk * e[jj + kx];
        }
      }
      u32 o[4];
#pragma unroll
      for (int q = 0; q < 4; ++q)
        o[q] = pack2(acc[2 * q], acc[2 * q + 1]);
      *(uint4*)&Ds[s1][ii] = make_uint4(o[0], o[1], o[2], o[3]);
    }
  }
  __syncthreads();

  // ---- msa phase (R12/R13-verified) ----
  const int lc   = t & 3;
  const int head = (t >> 2) & 7;
  const int win  = t >> 5;                     // 0..15
  const int chq  = head * 24 + lc * 6;         // even
  float qv[4][6], kv[4][6], vv[4][6];
#pragma unroll
  for (int s1 = 0; s1 < 2; ++s1) {
#pragma unroll
    for (int s2 = 0; s2 < 2; ++s2) {
      const int tt = s1 * 2 + s2;
      const int base = (2 * win + s2) * 576 + chq;
#pragma unroll
      for (int pp = 0; pp < 3; ++pp) {
        u32 aq = *(const u32*)&Ds[s1][base + 2 * pp];
        u32 ak = *(const u32*)&Ds[s1][base + 192 + 2 * pp];
        u32 av = *(const u32*)&Ds[s1][base + 384 + 2 * pp];
        qv[tt][2 * pp]     = bf2f((u16)(aq & 0xffffu));
        qv[tt][2 * pp + 1] = bf2f((u16)(aq >> 16));
        kv[tt][2 * pp]     = bf2f((u16)(ak & 0xffffu));
        kv[tt][2 * pp + 1] = bf2f((u16)(ak >> 16));
        vv[tt][2 * pp]     = bf2f((u16)(av & 0xffffu));
        vv[tt][2 * pp + 1] = bf2f((u16)(av >> 16));
      }
    }
  }
  float s[4][4];
#pragma unroll
  for (int tq = 0; tq < 4; ++tq) {
#pragma unroll
    for (int tk = 0; tk < 4; ++tk) {
      float d = 0.f;
#pragma unroll
      for (int dd = 0; dd < 6; ++dd) d += qv[tq][dd] * kv[tk][dd];
      d += __shfl_xor(d, 1);
      d += __shfl_xor(d, 2);
      s[tq][tk] = d * 0.35355339059327373f;    // SCALE = HEADS^-0.5
    }
  }
  u16* const ab = attnb + (size_t)b * 12582912;
#pragma unroll
  for (int tq = 0; tq < 4; ++tq) {
    float mx = fmaxf(fmaxf(s[tq][0], s[tq][1]), fmaxf(s[tq][2], s[tq][3]));
    float e0 = __expf(s[tq][0] - mx), e1 = __expf(s[tq][1] - mx);
    float e2 = __expf(s[tq][2] - mx), e3 = __expf(s[tq][3] - mx);
    float inv = 1.f / (e0 + e1 + e2 + e3);
    float a0 = e0 * inv, a1 = e1 * inv, a2 = e2 * inv, a3 = e3 * inv;
    float o6[6];
#pragma unroll
    for (int dd = 0; dd < 6; ++dd)
      o6[dd] = a0 * vv[0][dd] + a1 * vv[1][dd] + a2 * vv[2][dd] + a3 * vv[3][dd];
    const int s1 = tq >> 1, s2 = tq & 1;
    const size_t pg = (size_t)((2 * gh + s1) * 256) + c0 + 2 * win + s2;
    u16* dst = ab + pg * 192 + chq;
    *(u32*)(dst)     = pack2(o6[0], o6[1]);
    *(u32*)(dst + 2) = pack2(o6[2], o6[3]);
    *(u32*)(dst + 4) = pack2(o6[4], o6[5]);
  }
}

// ---------------- K4: proj 1x1 (GEMM M=192,K=192) + shuffle_back ----------
// (R14-verified: barrier-free direct scatter, swizzled LDS.)
__global__ __launch_bounds__(512) void k_proj(const u16* __restrict__ attnb,
                                              const u16* __restrict__ wp,
                                              float* __restrict__ out) {
  __shared__ __align__(16) u16 Xs[256 * 200];
  const int t  = threadIdx.x;
  const int b  = blockIdx.y;
  const int hs = blockIdx.x;
  const int pix = t & 255, cg = t >> 8;
  {
    const u16* ab = attnb + (size_t)b * 12582912 + (size_t)hs * 256 + pix;
    u16* xrow = &Xs[pix * 200];
    const int key = (pix >> 4) & 7;
#pragma unroll 8
    for (int i = 0; i < 96; i += 2) {
      const int c = cg * 96 + i;
      const int slot = c >> 3;
      const int sl = (slot & 24) | ((slot + key) & 7);
      u16 v0 = ab[(size_t)c * 65536];
      u16 v1 = ab[(size_t)(c + 1) * 65536];
      *(u32*)&xrow[sl * 8 + (c & 7)] = (u32)v0 | ((u32)v1 << 16);
    }
  }
  __syncthreads();
  const int lane = t & 63, wid = t >> 6;
  const int lm = lane & 15, lk = lane >> 4;
  s16x8 bv[2][6];
#pragma unroll
  for (int rp = 0; rp < 2; ++rp) {
    const int r = 2 * wid + rp;
#pragma unroll
    for (int kk = 0; kk < 6; ++kk) {
      const int slot = 4 * kk + lk;
      const int sl = (slot & 24) | ((slot + (lm & 7)) & 7);
      bv[rp][kk] = *(const s16x8*)&Xs[(16 * lm + r) * 200 + sl * 8];
    }
  }
  float* const ob = out + (size_t)b * 12582912;
  const int hq_base = hs >> 2;
  const int wq_base = (hs & 3) << 4;
  int hqr[2], wq0[2];
#pragma unroll
  for (int rp = 0; rp < 2; ++rp) {
    const int r = 2 * wid + rp;
    hqr[rp] = ((r >> 2) & 3) * 64 + hq_base;
    wq0[rp] = (r & 3) * 64 + wq_base;
  }

#pragma unroll 1
  for (int mt = 0; mt < 3; ++mt) {
    f32x4 acc[4][2];
#pragma unroll
    for (int i = 0; i < 4; ++i) {
      acc[i][0] = f32x4{0.f, 0.f, 0.f, 0.f};
      acc[i][1] = f32x4{0.f, 0.f, 0.f, 0.f};
    }
#pragma unroll
    for (int kk = 0; kk < 6; ++kk) {
      s16x8 af[4];
#pragma unroll
      for (int mf = 0; mf < 4; ++mf)
        af[mf] = *(const s16x8*)&wp[(size_t)(mt * 64 + mf * 16 + lm) * 192 + kk * 32 + lk * 8];
#pragma unroll
      for (int mf = 0; mf < 4; ++mf) {
#pragma unroll
        for (int rp = 0; rp < 2; ++rp)
          acc[mf][rp] = __builtin_amdgcn_mfma_f32_16x16x32_bf16(af[mf], bv[rp][kk], acc[mf][rp], 0, 0, 0);
      }
    }
#pragma unroll
    for (int mf = 0; mf < 4; ++mf) {
#pragma unroll
      for (int rp = 0; rp < 2; ++rp) {
        float* base = ob + (size_t)(mt * 64 + mf * 16 + lk * 4) * 65536
                         + (size_t)hqr[rp] * 256 + wq0[rp] + lm;
#pragma unroll
        for (int rr = 0; rr < 4; ++rr)
          base[(size_t)rr * 65536] = acc[mf][rp][rr];
      }
    }
  }
}

extern "C" void kernel_launch(void* const* d_in, const int* in_sizes, int n_in,
                              void* d_out, int out_size, void* d_ws, size_t ws_size,
                              hipStream_t stream) {
  const float* x   = (const float*)d_in[0];
  const float* wq  = (const float*)d_in[1];
  const float* wdw = (const float*)d_in[2];
  const float* wpr = (const float*)d_in[3];
  float* out = (float*)d_out;
  u16* ws = (u16*)d_ws;
  // layout (u16): wq_bf | wp_bf | qkv1 (302MB) | attnb (100MB)
  u16* wq_bf = ws;
  u16* wp_bf = ws + 110592;
  u16* qkv1  = ws + 147456;                       // 4*576*65536 bf16 (NCHW)
  u16* attnb = qkv1 + (size_t)150994944;          // 4*65536*192 bf16 (flat)

  hipLaunchKernelGGL(k_wcvt,  dim3(432), dim3(256), 0, stream, wq, wpr, wq_bf, wp_bf);
  hipLaunchKernelGGL(k_qkv,   dim3(256, 4), dim3(768), 0, stream, x, wq_bf, qkv1);
  hipLaunchKernelGGL(k_dwmsa, dim3(1024, 4), dim3(512), 0, stream, qkv1, wdw, attnb);
  hipLaunchKernelGGL(k_proj,  dim3(256, 4), dim3(512), 0, stream, attnb, wp_bf, out);
}